// Round 1
// baseline (65138.666 us; speedup 1.0000x reference)
//
#include <hip/hip_runtime.h>
#include <math.h>

#define D_IN  1024
#define H_DIM 2048
#define H3    6144
#define T_SEQ 4096
#define S_SEQ 4095

// ---------------------------------------------------------------------------
// Tiled fp32 GEMM: C[M,N] = op(A)[M,K] @ B[N,K]^T + bias[N]
//   Atrans=1: A(m,k) = A[k*lda + m]   (used for gx: A = X, lda = T)
//   Atrans=0: A(m,k) = A[m*lda + k]   (used for yhat: A = log_h, lda = H)
// 64x64 tile, K-chunk 16, 256 threads, each computes 4x4.
// ---------------------------------------------------------------------------
#define TS 64
#define KS 16
#define LSTR 68   // padded LDS row stride (keeps 16B alignment, spreads banks)

__global__ __launch_bounds__(256) void gemm_bias(
    const float* __restrict__ A, const float* __restrict__ B,
    const float* __restrict__ bias, float* __restrict__ C,
    int M, int N, int K, int lda, int Atrans)
{
    __shared__ __align__(16) float As[KS * LSTR];
    __shared__ __align__(16) float Bs[KS * LSTR];
    const int tid = threadIdx.x;
    const int m0 = blockIdx.x * TS;
    const int n0 = blockIdx.y * TS;
    const int tx = tid & 15, ty = tid >> 4;
    float c[4][4] = {};

    for (int k0 = 0; k0 < K; k0 += KS) {
        if (Atrans) {
            const int ml = tid & 63;
            const int kb = tid >> 6;           // 0..3
            #pragma unroll
            for (int kk = 0; kk < KS; kk += 4) {
                const int m = m0 + ml;
                As[(kk + kb) * LSTR + ml] =
                    (m < M) ? A[(size_t)(k0 + kk + kb) * lda + m] : 0.f;
            }
        } else {
            const int kl = tid & 15;
            const int mb = tid >> 4;           // 0..15
            #pragma unroll
            for (int ml = 0; ml < TS; ml += 16) {
                const int m = m0 + ml + mb;
                As[kl * LSTR + ml + mb] =
                    (m < M) ? A[(size_t)m * lda + (k0 + kl)] : 0.f;
            }
        }
        {
            const int kl = tid & 15;
            const int nb = tid >> 4;           // 0..15
            #pragma unroll
            for (int nl = 0; nl < TS; nl += 16) {
                Bs[kl * LSTR + nl + nb] = B[(size_t)(n0 + nl + nb) * K + (k0 + kl)];
            }
        }
        __syncthreads();
        #pragma unroll
        for (int kk = 0; kk < KS; ++kk) {
            const float4 a = *(const float4*)&As[kk * LSTR + tx * 4];
            const float4 b = *(const float4*)&Bs[kk * LSTR + ty * 4];
            c[0][0] += a.x * b.x; c[0][1] += a.x * b.y; c[0][2] += a.x * b.z; c[0][3] += a.x * b.w;
            c[1][0] += a.y * b.x; c[1][1] += a.y * b.y; c[1][2] += a.y * b.z; c[1][3] += a.y * b.w;
            c[2][0] += a.z * b.x; c[2][1] += a.z * b.y; c[2][2] += a.z * b.z; c[2][3] += a.z * b.w;
            c[3][0] += a.w * b.x; c[3][1] += a.w * b.y; c[3][2] += a.w * b.z; c[3][3] += a.w * b.w;
        }
        __syncthreads();
    }
    #pragma unroll
    for (int i = 0; i < 4; ++i) {
        const int m = m0 + tx * 4 + i;
        if (m < M) {
            #pragma unroll
            for (int j = 0; j < 4; ++j) {
                const int n = n0 + ty * 4 + j;
                C[(size_t)m * N + n] = c[i][j] + bias[n];
            }
        }
    }
}

// ---------------------------------------------------------------------------
// One GRU time step. Block j (2048 blocks) computes h_new[j].
// 3 waves: wave w computes gh row (j + w*H) as a float4 dot over LDS-staged h.
// gx_t: precomputed input-gate row for this t (includes b_i2h), or nullptr ->
//        compute on the fly from W_i2h and X column t.
// ---------------------------------------------------------------------------
__global__ __launch_bounds__(192) void gru_step(
    const float* __restrict__ Whh, const float* __restrict__ bhh,
    const float* __restrict__ gx_t,
    const float* __restrict__ Wih, const float* __restrict__ bih,
    const float* __restrict__ X, int t,
    const float* __restrict__ h_prev, float* __restrict__ h_out)
{
    __shared__ __align__(16) float hs[H_DIM];
    __shared__ float red[3], gred[3];
    const int tid = threadIdx.x;
    for (int i = tid; i < H_DIM; i += 192) hs[i] = h_prev[i];
    __syncthreads();

    const int w = tid >> 6, lane = tid & 63;
    const int j = blockIdx.x;
    const int row = j + w * H_DIM;

    const float4* Wr = (const float4*)(Whh + (size_t)row * H_DIM);
    const float4* h4 = (const float4*)hs;
    float acc = 0.f;
    #pragma unroll
    for (int k = 0; k < H_DIM / 256; ++k) {      // 8 iters of float4
        const float4 wv = Wr[lane + 64 * k];
        const float4 hv = h4[lane + 64 * k];
        acc += wv.x * hv.x + wv.y * hv.y + wv.z * hv.z + wv.w * hv.w;
    }
    float gacc = 0.f;
    if (gx_t == nullptr) {
        const float* Wi = Wih + (size_t)row * D_IN;
        #pragma unroll
        for (int k = 0; k < D_IN / 64; ++k) {
            const int d = lane + 64 * k;
            gacc += Wi[d] * X[(size_t)d * T_SEQ + t];
        }
    }
    #pragma unroll
    for (int off = 32; off > 0; off >>= 1) {
        acc  += __shfl_xor(acc, off);
        gacc += __shfl_xor(gacc, off);
    }
    if (lane == 0) {
        red[w]  = acc + bhh[row];
        gred[w] = gacc + ((gx_t == nullptr) ? bih[row] : 0.f);
    }
    __syncthreads();
    if (tid == 0) {
        float i_r, i_i, i_n;
        if (gx_t) { i_r = gx_t[j]; i_i = gx_t[j + H_DIM]; i_n = gx_t[j + 2 * H_DIM]; }
        else      { i_r = gred[0]; i_i = gred[1]; i_n = gred[2]; }
        const float h_r = red[0], h_i = red[1], h_n = red[2];
        const float rg = 1.f / (1.f + expf(-(i_r + h_r)));
        const float ig = 1.f / (1.f + expf(-(i_i + h_i)));
        const float ng = tanhf(i_n + rg * h_n);
        h_out[j] = ng + ig * (hs[j] - ng);
    }
}

// ---------------------------------------------------------------------------
// Per-step loss + Pearson correlation. Block t over 1024 dims.
// y_t[d] = X[d*T + (t+1)]
// ---------------------------------------------------------------------------
__global__ __launch_bounds__(256) void loss_acc(
    const float* __restrict__ X, const float* __restrict__ yhat_all,
    float* __restrict__ log_loss, float* __restrict__ log_acc)
{
    const int t = blockIdx.x;
    const float* yh = yhat_all + (size_t)t * D_IN;
    const int tid = threadIdx.x;
    float s_y = 0, s_p = 0, s_yy = 0, s_pp = 0, s_yp = 0, s_d2 = 0;
    for (int d = tid; d < D_IN; d += 256) {
        const float y = X[(size_t)d * T_SEQ + (t + 1)];
        const float p = yh[d];
        const float df = y - p;
        s_y += y; s_p += p; s_yy += y * y; s_pp += p * p; s_yp += y * p; s_d2 += df * df;
    }
    #pragma unroll
    for (int off = 32; off > 0; off >>= 1) {
        s_y  += __shfl_xor(s_y, off);  s_p  += __shfl_xor(s_p, off);
        s_yy += __shfl_xor(s_yy, off); s_pp += __shfl_xor(s_pp, off);
        s_yp += __shfl_xor(s_yp, off); s_d2 += __shfl_xor(s_d2, off);
    }
    __shared__ float red[4][6];
    const int w = tid >> 6;
    if ((tid & 63) == 0) {
        red[w][0] = s_y; red[w][1] = s_p; red[w][2] = s_yy;
        red[w][3] = s_pp; red[w][4] = s_yp; red[w][5] = s_d2;
    }
    __syncthreads();
    if (tid == 0) {
        float a = 0, b = 0, cc = 0, dd = 0, e = 0, f = 0;
        for (int i = 0; i < 4; ++i) {
            a += red[i][0]; b += red[i][1]; cc += red[i][2];
            dd += red[i][3]; e += red[i][4]; f += red[i][5];
        }
        const float n = (float)D_IN;
        log_loss[t] = f / n;
        const float cov = e - a * b / n;
        const float vy  = cc - a * a / n;
        const float vp  = dd - b * b / n;
        log_acc[t] = cov / (sqrtf(vy) * sqrtf(vp));
    }
}

__global__ __launch_bounds__(256) void loss_sum(
    const float* __restrict__ log_loss, float* __restrict__ out)
{
    float s = 0;
    for (int i = threadIdx.x; i < S_SEQ; i += 256) s += log_loss[i];
    #pragma unroll
    for (int off = 32; off > 0; off >>= 1) s += __shfl_xor(s, off);
    __shared__ float red[4];
    if ((threadIdx.x & 63) == 0) red[threadIdx.x >> 6] = s;
    __syncthreads();
    if (threadIdx.x == 0) out[0] = red[0] + red[1] + red[2] + red[3];
}

// ---------------------------------------------------------------------------
extern "C" void kernel_launch(void* const* d_in, const int* in_sizes, int n_in,
                              void* d_out, int out_size, void* d_ws, size_t ws_size,
                              hipStream_t stream)
{
    const float* X   = (const float*)d_in[0];
    const float* h0  = (const float*)d_in[1];
    const float* Wih = (const float*)d_in[2];
    const float* bih = (const float*)d_in[3];
    const float* Whh = (const float*)d_in[4];
    const float* bhh = (const float*)d_in[5];
    const float* Who = (const float*)d_in[6];
    const float* bho = (const float*)d_in[7];

    float* out       = (float*)d_out;
    float* loss_out  = out;                               // [1]
    float* log_loss  = out + 1;                           // [4095]
    float* log_acc   = out + 1 + S_SEQ;                   // [4095]
    float* log_h     = out + 1 + 2 * S_SEQ;               // [4095*2048]
    float* log_yhat  = log_h + (size_t)S_SEQ * H_DIM;     // [4095*1024]

    const size_t gx_bytes = (size_t)S_SEQ * H3 * sizeof(float);
    float* gx = (ws_size >= gx_bytes) ? (float*)d_ws : nullptr;

    // Phase 1: gx_all = x_seq @ W_i2h^T + b_i2h   (parallel, no recurrence)
    if (gx) {
        dim3 g((S_SEQ + TS - 1) / TS, H3 / TS);
        gemm_bias<<<g, 256, 0, stream>>>(X, Wih, bih, gx, S_SEQ, H3, D_IN, T_SEQ, 1);
    }

    // Phase 2: sequential scan — only h carries the recurrence.
    for (int t = 0; t < S_SEQ; ++t) {
        const float* hp = (t == 0) ? h0 : (log_h + (size_t)(t - 1) * H_DIM);
        gru_step<<<H_DIM, 192, 0, stream>>>(
            Whh, bhh, gx ? gx + (size_t)t * H3 : nullptr,
            Wih, bih, X, t, hp, log_h + (size_t)t * H_DIM);
    }

    // Phase 3: log_yhat = log_h @ W_h2o^T + b_h2o  (one big GEMM)
    {
        dim3 g((S_SEQ + TS - 1) / TS, D_IN / TS);
        gemm_bias<<<g, 256, 0, stream>>>(log_h, Who, bho, log_yhat, S_SEQ, D_IN, H_DIM, H_DIM, 0);
    }

    // Phase 4: per-step loss + Pearson corr, then total loss.
    loss_acc<<<S_SEQ, 256, 0, stream>>>(X, log_yhat, log_loss, log_acc);
    loss_sum<<<1, 256, 0, stream>>>(log_loss, loss_out);
}